// Round 15
// baseline (111.021 us; speedup 1.0000x reference)
//
#include <hip/hip_runtime.h>

typedef _Float16 f16;
typedef __attribute__((ext_vector_type(2))) __fp16 fp16x2;
typedef __attribute__((ext_vector_type(8))) _Float16 f16x8;
typedef __attribute__((ext_vector_type(4))) float f32x4;
typedef __attribute__((ext_vector_type(4))) unsigned int u32x4;

#define NPTS   (16 * 32768)
// packed-weight layout in d_ws (bytes); weights stay in global (L2-resident, ~80KB)
#define W0P_OFF 0
#define W1P_OFF (16 * 1024)
#define W2P_OFF (48 * 1024)
#define WOP_OFF (80 * 1024)
#define FRAGS_BYTES (84 * 1024)
#define TENC_OFF FRAGS_BYTES          // in ws: 16 batches x 16 f32
#define WS_NEEDED (FRAGS_BYTES + 1024)
// LDS: one wave per block -> single 4KB transpose scratch
#define LDS_TOTAL 4096

// ---------------- pack kernel: weights -> f16 A-operand fragments (W^T) ----------------
// A frag (mt,kt): lane l, elem j <-> W_sw[m = 16mt + (l&15)][k] = W[k][m]
//   layer0 (natural k-map, matches layer-0 B build): k = 32kt + 8*(l>>4) + j
//   layers 1,2,out (chained from D layout):          k = 32kt + 16*(j>>2) + 4*(l>>4) + (j&3)
__global__ void pack_weights(const float* __restrict__ time, const float* __restrict__ te0,
                             const float* __restrict__ te1, const float* __restrict__ W0,
                             const float* __restrict__ W1, const float* __restrict__ W2,
                             const float* __restrict__ Wout, unsigned char* __restrict__ ws) {
  const int bi = blockIdx.x;
  const int l = threadIdx.x;
  const int g = l >> 4, r16 = l & 15;
  if (bi < 84) {
    const float* W; int obase, fi, kt, mt, kmax; bool natural, outcol;
    if (bi < 16)      { W = W0;   fi = bi;      mt = fi >> 1; kt = fi & 1; obase = W0P_OFF; kmax = 55;  natural = true;  outcol = false; }
    else if (bi < 48) { W = W1;   fi = bi - 16; mt = fi >> 2; kt = fi & 3; obase = W1P_OFF; kmax = 128; natural = false; outcol = false; }
    else if (bi < 80) { W = W2;   fi = bi - 48; mt = fi >> 2; kt = fi & 3; obase = W2P_OFF; kmax = 128; natural = false; outcol = false; }
    else              { W = Wout; fi = bi - 80; mt = 0;       kt = fi;     obase = WOP_OFF; kmax = 128; natural = false; outcol = true;  }
    const int m = mt * 16 + r16;
    f16 vals[8] __attribute__((aligned(16)));
#pragma unroll
    for (int j = 0; j < 8; ++j) {
      const int k = natural ? (kt * 32 + g * 8 + j)
                            : (kt * 32 + (j >> 2) * 16 + g * 4 + (j & 3));
      float v = 0.f;
      if (k < kmax) v = outcol ? ((m == 0) ? Wout[k] : 0.f) : W[k * 128 + m];
      vals[j] = (f16)v;
    }
    *(u32x4*)(ws + obase + (fi * 64 + l) * 16) = *(const u32x4*)vals;
  } else {
    // time encoding: 16 batches x 16 dims fp32
    const int idx = (bi - 84) * 64 + l;  // 0..255
    const int b = idx >> 4, d = idx & 15;
    const float t = time[b];
    const float* emb; int L, dd;
    if (d < 8) { emb = te0; L = 5;  dd = d; }
    else       { emb = te1; L = 20; dd = d - 8; }
    const float tL = t * (float)L;
    int i = (int)floorf(tL);
    i = i < 0 ? 0 : (i > L - 1 ? L - 1 : i);
    const float wlo = (float)(i + 1) - tL;
    float v = wlo * emb[i * 8 + dd] + (1.f - wlo) * emb[(i + 1) * 8 + dd];
    if (t >= 1.f) v = emb[L * 8 + dd];
    ((float*)(ws + TENC_OFF))[idx] = v;
  }
}

// packed relu: max of two f16 halves vs 0 (exact: relu commutes with RTZ rounding)
__device__ __forceinline__ unsigned int pkmax0(unsigned int x) {
  unsigned int r;
  asm("v_pk_max_f16 %0, %1, %2" : "=v"(r) : "v"(x), "v"(0u));
  return r;
}
__device__ __forceinline__ unsigned int pkrtz(float a, float b) {
  union { fp16x2 h; unsigned int u; } c;
  c.h = __builtin_amdgcn_cvt_pkrtz(a, b);
  return c.u;
}

// ---------------- one swapped hidden layer: D = W_sw(128xK) * Bin(Kx64) ----------------
// A-frags stream from L2 with the r8 2-deep rotating prefetch. Bias loaded at kt==0,
// applied in the kt==KT-1 epilogue via pack-then-pk_max (VALU diet: 128 ops vs 192).
template <int KT>
__device__ __forceinline__ void layer_swapped(const unsigned char* __restrict__ wsrc,
                                              const float* __restrict__ bias,
                                              const f16x8 (&Bin)[KT][4], f16x8 (&Bout)[4][4],
                                              int lane) {
  const int g4 = (lane >> 4) * 4;
  f16x8 A0b[3], A1b[3];
  float4 ba, bb;
  f32x4 acc[2][4];
  // prologue: preload steps 0,1
#pragma unroll
  for (int s = 0; s < 2; ++s) {
    const int mtp = s / KT, kt = s % KT;
    A0b[s] = *(const f16x8*)(wsrc + (((2 * mtp)     * KT + kt) * 64 + lane) * 16);
    A1b[s] = *(const f16x8*)(wsrc + (((2 * mtp + 1) * KT + kt) * 64 + lane) * 16);
  }
#pragma unroll
  for (int s = 0; s < 4 * KT; ++s) {
    const int mtp = s / KT, kt = s % KT, cb = s % 3;
    if (kt == 0) {
      ba = *(const float4*)(bias + mtp * 32 + g4);
      bb = *(const float4*)(bias + mtp * 32 + 16 + g4);
#pragma unroll
      for (int nt = 0; nt < 4; ++nt) {
        acc[0][nt] = (f32x4){ba.x, ba.y, ba.z, ba.w};
        acc[1][nt] = (f32x4){bb.x, bb.y, bb.z, bb.w};
      }
    }
    // prefetch step s+2
    if (s + 2 < 4 * KT) {
      const int mtp2 = (s + 2) / KT, kt2 = (s + 2) % KT, pb = (s + 2) % 3;
      A0b[pb] = *(const f16x8*)(wsrc + (((2 * mtp2)     * KT + kt2) * 64 + lane) * 16);
      A1b[pb] = *(const f16x8*)(wsrc + (((2 * mtp2 + 1) * KT + kt2) * 64 + lane) * 16);
    }
    __builtin_amdgcn_s_setprio(1);
#pragma unroll
    for (int nt = 0; nt < 4; ++nt)
      acc[0][nt] = __builtin_amdgcn_mfma_f32_16x16x32_f16(A0b[cb], Bin[kt][nt], acc[0][nt], 0, 0, 0);
#pragma unroll
    for (int nt = 0; nt < 4; ++nt)
      acc[1][nt] = __builtin_amdgcn_mfma_f32_16x16x32_f16(A1b[cb], Bin[kt][nt], acc[1][nt], 0, 0, 0);
    __builtin_amdgcn_s_setprio(0);
    if (kt == KT - 1) {
#pragma unroll
      for (int nt = 0; nt < 4; ++nt) {
        union { unsigned int w[4]; f16x8 v; } u;
        u.w[0] = pkmax0(pkrtz(acc[0][nt][0], acc[0][nt][1]));
        u.w[1] = pkmax0(pkrtz(acc[0][nt][2], acc[0][nt][3]));
        u.w[2] = pkmax0(pkrtz(acc[1][nt][0], acc[1][nt][1]));
        u.w[3] = pkmax0(pkrtz(acc[1][nt][2], acc[1][nt][3]));
        Bout[mtp][nt] = u.v;
      }
    }
  }
}

// ---------------- fused main kernel: SINGLE-WAVE blocks (64 thr), weights from L2 ----------------
// 1-wave workgroups: residency granularity = CU workgroup slots (typically 16/CU),
// not multi-wave block packing. LDS 4KB/block, regs ~140/wave -> slots bind first.
__global__ void __launch_bounds__(64, 4)
mlp_main(const float* __restrict__ xyz, const float* __restrict__ b0,
         const float* __restrict__ b1, const float* __restrict__ b2,
         const float* __restrict__ bout, const unsigned char* __restrict__ ws,
         float* __restrict__ out) {
  extern __shared__ char lds[];
  const int lane = threadIdx.x;
  const int g = lane >> 4, r16 = lane & 15;

  char* scr = lds;  // this wave's private transpose scratch (32 rows x 128B)
  const float bo = bout[0];

  const int pbase = blockIdx.x * 64;
  const int p = pbase + lane;

  // ---- 64-dim feature row in f32, then pack pairs with cvt_pkrtz ----
  float ff[64];
  const float* tb = (const float*)(ws + TENC_OFF) + (blockIdx.x >> 9) * 16;  // batch = p/32768
#pragma unroll
  for (int i = 0; i < 16; ++i) ff[i] = tb[i];
  const float xs0 = xyz[p * 3], xs1 = xyz[p * 3 + 1], xs2 = xyz[p * 3 + 2];
  const float pcs[3] = {(xs0 + 1.f) * 0.5f, (xs1 + 1.f) * 0.5f, (xs2 + 1.f) * 0.5f};
#pragma unroll
  for (int c = 0; c < 3; ++c) {
    ff[16 + c] = pcs[c];
    float s = __sinf(pcs[c]), co = __cosf(pcs[c]);
#pragma unroll
    for (int f = 0; f < 6; ++f) {
      ff[19 + f * 3 + c] = s;
      ff[37 + f * 3 + c] = co;
      const float s2 = 2.f * s * co, c2 = 1.f - 2.f * s * s;
      s = s2; co = c2;
    }
  }
#pragma unroll
  for (int i = 55; i < 64; ++i) ff[i] = 0.f;
  unsigned int fw[32];
#pragma unroll
  for (int i = 0; i < 32; ++i) fw[i] = pkrtz(ff[2 * i], ff[2 * i + 1]);

  // ---- transpose via scratch, two 32-point halves (wave-internal sync) ----
  f16x8 B0[2][4];
#pragma unroll
  for (int h = 0; h < 2; ++h) {
    if ((lane >> 5) == h) {
#pragma unroll
      for (int s = 0; s < 8; ++s)
        *(u32x4*)(scr + (lane & 31) * 128 + ((s ^ (lane & 7)) * 16)) = ((const u32x4*)fw)[s];
    }
    asm volatile("s_waitcnt lgkmcnt(0)" ::: "memory");
#pragma unroll
    for (int kt = 0; kt < 2; ++kt)
#pragma unroll
      for (int nn = 0; nn < 2; ++nn) {
        const int row = nn * 16 + r16;
        B0[kt][h * 2 + nn] = *(const f16x8*)(scr + row * 128 + (((4 * kt + g) ^ (row & 7)) * 16));
      }
    asm volatile("s_waitcnt lgkmcnt(0)" ::: "memory");
  }

  // ---- 3 hidden layers fully in registers, weights streamed from L2 w/ prefetch ----
  f16x8 Bx[4][4], By[4][4];
  layer_swapped<2>(ws + W0P_OFF, b0, B0, Bx, lane);
  layer_swapped<4>(ws + W1P_OFF, b1, Bx, By, lane);
  layer_swapped<4>(ws + W2P_OFF, b2, By, Bx, lane);

  // ---- output layer (M=16 padded, only row 0 real): preload all 4 frags, bias as C ----
  f16x8 Ab[4];
#pragma unroll
  for (int kt = 0; kt < 4; ++kt)
    Ab[kt] = *(const f16x8*)(ws + WOP_OFF + (kt * 64 + lane) * 16);
  const f32x4 bovec = (f32x4){bo, bo, bo, bo};
  f32x4 accO[4];
  __builtin_amdgcn_s_setprio(1);
#pragma unroll
  for (int nt = 0; nt < 4; ++nt)
    accO[nt] = __builtin_amdgcn_mfma_f32_16x16x32_f16(Ab[0], Bx[0][nt], bovec, 0, 0, 0);
#pragma unroll
  for (int kt = 1; kt < 4; ++kt) {
#pragma unroll
    for (int nt = 0; nt < 4; ++nt)
      accO[nt] = __builtin_amdgcn_mfma_f32_16x16x32_f16(Ab[kt], Bx[kt][nt], accO[nt], 0, 0, 0);
  }
  __builtin_amdgcn_s_setprio(0);

  // ---- coalesced store: broadcast row-0 values, one 256B wave store ----
  const float a0 = __shfl(accO[0][0], r16, 64);
  const float a1 = __shfl(accO[1][0], r16, 64);
  const float a2 = __shfl(accO[2][0], r16, 64);
  const float a3 = __shfl(accO[3][0], r16, 64);
  const float v = g == 0 ? a0 : g == 1 ? a1 : g == 2 ? a2 : a3;
  out[pbase + lane] = v;
}

extern "C" void kernel_launch(void* const* d_in, const int* in_sizes, int n_in,
                              void* d_out, int out_size, void* d_ws, size_t ws_size,
                              hipStream_t stream) {
  const float* time = (const float*)d_in[0];
  const float* xyz  = (const float*)d_in[1];
  const float* te0  = (const float*)d_in[2];
  const float* te1  = (const float*)d_in[3];
  const float* W0   = (const float*)d_in[4];
  const float* b0   = (const float*)d_in[5];
  const float* W1   = (const float*)d_in[6];
  const float* b1   = (const float*)d_in[7];
  const float* W2   = (const float*)d_in[8];
  const float* b2   = (const float*)d_in[9];
  const float* Wout = (const float*)d_in[10];
  const float* bout = (const float*)d_in[11];
  float* out = (float*)d_out;
  unsigned char* ws = (unsigned char*)d_ws;
  if (ws_size < WS_NEEDED) return;

  pack_weights<<<88, 64, 0, stream>>>(time, te0, te1, W0, W1, W2, Wout, ws);
  mlp_main<<<NPTS / 64, 64, LDS_TOTAL, stream>>>(xyz, b0, b1, b2, bout, ws, out);
}

// Round 16
// 46.751 us; speedup vs baseline: 2.3748x; 2.3748x over previous
//
#include <hip/hip_runtime.h>

typedef _Float16 f16;
typedef __attribute__((ext_vector_type(2))) __fp16 fp16x2;
typedef __attribute__((ext_vector_type(8))) _Float16 f16x8;
typedef __attribute__((ext_vector_type(4))) float f32x4;
typedef __attribute__((ext_vector_type(4))) unsigned int u32x4;

#define NPTS   (16 * 32768)
// packed-weight layout in d_ws (bytes); weights stay in global (L2-resident, ~80KB)
#define W0P_OFF 0
#define W1P_OFF (16 * 1024)
#define W2P_OFF (48 * 1024)
#define WOP_OFF (80 * 1024)
#define FRAGS_BYTES (84 * 1024)
#define TENC_OFF FRAGS_BYTES          // in ws: 16 batches x 16 f32
#define WS_NEEDED (FRAGS_BYTES + 1024)
// LDS: one wave per block -> single 4KB transpose scratch
#define LDS_TOTAL 4096

// ---------------- pack kernel: weights -> f16 A-operand fragments (W^T) ----------------
// A frag (mt,kt): lane l, elem j <-> W_sw[m = 16mt + (l&15)][k] = W[k][m]
//   layer0 (natural k-map, matches layer-0 B build): k = 32kt + 8*(l>>4) + j
//   layers 1,2,out (chained from D layout):          k = 32kt + 16*(j>>2) + 4*(l>>4) + (j&3)
__global__ void pack_weights(const float* __restrict__ time, const float* __restrict__ te0,
                             const float* __restrict__ te1, const float* __restrict__ W0,
                             const float* __restrict__ W1, const float* __restrict__ W2,
                             const float* __restrict__ Wout, unsigned char* __restrict__ ws) {
  const int bi = blockIdx.x;
  const int l = threadIdx.x;
  const int g = l >> 4, r16 = l & 15;
  if (bi < 84) {
    const float* W; int obase, fi, kt, mt, kmax; bool natural, outcol;
    if (bi < 16)      { W = W0;   fi = bi;      mt = fi >> 1; kt = fi & 1; obase = W0P_OFF; kmax = 55;  natural = true;  outcol = false; }
    else if (bi < 48) { W = W1;   fi = bi - 16; mt = fi >> 2; kt = fi & 3; obase = W1P_OFF; kmax = 128; natural = false; outcol = false; }
    else if (bi < 80) { W = W2;   fi = bi - 48; mt = fi >> 2; kt = fi & 3; obase = W2P_OFF; kmax = 128; natural = false; outcol = false; }
    else              { W = Wout; fi = bi - 80; mt = 0;       kt = fi;     obase = WOP_OFF; kmax = 128; natural = false; outcol = true;  }
    const int m = mt * 16 + r16;
    f16 vals[8] __attribute__((aligned(16)));
#pragma unroll
    for (int j = 0; j < 8; ++j) {
      const int k = natural ? (kt * 32 + g * 8 + j)
                            : (kt * 32 + (j >> 2) * 16 + g * 4 + (j & 3));
      float v = 0.f;
      if (k < kmax) v = outcol ? ((m == 0) ? Wout[k] : 0.f) : W[k * 128 + m];
      vals[j] = (f16)v;
    }
    *(u32x4*)(ws + obase + (fi * 64 + l) * 16) = *(const u32x4*)vals;
  } else {
    // time encoding: 16 batches x 16 dims fp32
    const int idx = (bi - 84) * 64 + l;  // 0..255
    const int b = idx >> 4, d = idx & 15;
    const float t = time[b];
    const float* emb; int L, dd;
    if (d < 8) { emb = te0; L = 5;  dd = d; }
    else       { emb = te1; L = 20; dd = d - 8; }
    const float tL = t * (float)L;
    int i = (int)floorf(tL);
    i = i < 0 ? 0 : (i > L - 1 ? L - 1 : i);
    const float wlo = (float)(i + 1) - tL;
    float v = wlo * emb[i * 8 + dd] + (1.f - wlo) * emb[(i + 1) * 8 + dd];
    if (t >= 1.f) v = emb[L * 8 + dd];
    ((float*)(ws + TENC_OFF))[idx] = v;
  }
}

// packed relu: max of two f16 halves vs 0 (exact: relu commutes with RTZ rounding)
__device__ __forceinline__ unsigned int pkmax0(unsigned int x) {
  unsigned int r;
  asm("v_pk_max_f16 %0, %1, %2" : "=v"(r) : "v"(x), "v"(0u));
  return r;
}
__device__ __forceinline__ unsigned int pkrtz(float a, float b) {
  union { fp16x2 h; unsigned int u; } c;
  c.h = __builtin_amdgcn_cvt_pkrtz(a, b);
  return c.u;
}

// ---------------- one swapped hidden layer: D = W_sw(128xK) * Bin(Kx64) ----------------
// A-frags stream from L2 with the r8 2-deep rotating prefetch. Bias loaded at kt==0,
// applied in the kt==KT-1 epilogue via pack-then-pk_max (VALU diet: 128 ops vs 192).
template <int KT>
__device__ __forceinline__ void layer_swapped(const unsigned char* __restrict__ wsrc,
                                              const float* __restrict__ bias,
                                              const f16x8 (&Bin)[KT][4], f16x8 (&Bout)[4][4],
                                              int lane) {
  const int g4 = (lane >> 4) * 4;
  f16x8 A0b[3], A1b[3];
  float4 ba, bb;
  f32x4 acc[2][4];
  // prologue: preload steps 0,1
#pragma unroll
  for (int s = 0; s < 2; ++s) {
    const int mtp = s / KT, kt = s % KT;
    A0b[s] = *(const f16x8*)(wsrc + (((2 * mtp)     * KT + kt) * 64 + lane) * 16);
    A1b[s] = *(const f16x8*)(wsrc + (((2 * mtp + 1) * KT + kt) * 64 + lane) * 16);
  }
#pragma unroll
  for (int s = 0; s < 4 * KT; ++s) {
    const int mtp = s / KT, kt = s % KT, cb = s % 3;
    if (kt == 0) {
      ba = *(const float4*)(bias + mtp * 32 + g4);
      bb = *(const float4*)(bias + mtp * 32 + 16 + g4);
#pragma unroll
      for (int nt = 0; nt < 4; ++nt) {
        acc[0][nt] = (f32x4){ba.x, ba.y, ba.z, ba.w};
        acc[1][nt] = (f32x4){bb.x, bb.y, bb.z, bb.w};
      }
    }
    // prefetch step s+2
    if (s + 2 < 4 * KT) {
      const int mtp2 = (s + 2) / KT, kt2 = (s + 2) % KT, pb = (s + 2) % 3;
      A0b[pb] = *(const f16x8*)(wsrc + (((2 * mtp2)     * KT + kt2) * 64 + lane) * 16);
      A1b[pb] = *(const f16x8*)(wsrc + (((2 * mtp2 + 1) * KT + kt2) * 64 + lane) * 16);
    }
    __builtin_amdgcn_s_setprio(1);
#pragma unroll
    for (int nt = 0; nt < 4; ++nt)
      acc[0][nt] = __builtin_amdgcn_mfma_f32_16x16x32_f16(A0b[cb], Bin[kt][nt], acc[0][nt], 0, 0, 0);
#pragma unroll
    for (int nt = 0; nt < 4; ++nt)
      acc[1][nt] = __builtin_amdgcn_mfma_f32_16x16x32_f16(A1b[cb], Bin[kt][nt], acc[1][nt], 0, 0, 0);
    __builtin_amdgcn_s_setprio(0);
    if (kt == KT - 1) {
#pragma unroll
      for (int nt = 0; nt < 4; ++nt) {
        union { unsigned int w[4]; f16x8 v; } u;
        u.w[0] = pkmax0(pkrtz(acc[0][nt][0], acc[0][nt][1]));
        u.w[1] = pkmax0(pkrtz(acc[0][nt][2], acc[0][nt][3]));
        u.w[2] = pkmax0(pkrtz(acc[1][nt][0], acc[1][nt][1]));
        u.w[3] = pkmax0(pkrtz(acc[1][nt][2], acc[1][nt][3]));
        Bout[mtp][nt] = u.v;
      }
    }
  }
}

// ---------------- fused main kernel: SINGLE-WAVE blocks (64 thr), weights from L2 ----------------
// 1-wave workgroups raise residency via CU workgroup slots (r15: occupancy 18->38%).
// __launch_bounds__(64,1): allocator law budget = 2048/(waves x min_blocks) -> 2048,
// i.e. UNCONSTRAINED (r0's (256,1) -> 180 used, zero spill). Any min_blocks>1 re-caps
// VGPR at 64 and spills (r15: 113MB fetch, 121us).
__global__ void __launch_bounds__(64, 1)
mlp_main(const float* __restrict__ xyz, const float* __restrict__ b0,
         const float* __restrict__ b1, const float* __restrict__ b2,
         const float* __restrict__ bout, const unsigned char* __restrict__ ws,
         float* __restrict__ out) {
  extern __shared__ char lds[];
  const int lane = threadIdx.x;
  const int g = lane >> 4, r16 = lane & 15;

  char* scr = lds;  // this wave's private transpose scratch (32 rows x 128B)
  const float bo = bout[0];

  const int pbase = blockIdx.x * 64;
  const int p = pbase + lane;

  // ---- 64-dim feature row in f32, then pack pairs with cvt_pkrtz ----
  float ff[64];
  const float* tb = (const float*)(ws + TENC_OFF) + (blockIdx.x >> 9) * 16;  // batch = p/32768
#pragma unroll
  for (int i = 0; i < 16; ++i) ff[i] = tb[i];
  const float xs0 = xyz[p * 3], xs1 = xyz[p * 3 + 1], xs2 = xyz[p * 3 + 2];
  const float pcs[3] = {(xs0 + 1.f) * 0.5f, (xs1 + 1.f) * 0.5f, (xs2 + 1.f) * 0.5f};
#pragma unroll
  for (int c = 0; c < 3; ++c) {
    ff[16 + c] = pcs[c];
    float s = __sinf(pcs[c]), co = __cosf(pcs[c]);
#pragma unroll
    for (int f = 0; f < 6; ++f) {
      ff[19 + f * 3 + c] = s;
      ff[37 + f * 3 + c] = co;
      const float s2 = 2.f * s * co, c2 = 1.f - 2.f * s * s;
      s = s2; co = c2;
    }
  }
#pragma unroll
  for (int i = 55; i < 64; ++i) ff[i] = 0.f;
  unsigned int fw[32];
#pragma unroll
  for (int i = 0; i < 32; ++i) fw[i] = pkrtz(ff[2 * i], ff[2 * i + 1]);

  // ---- transpose via scratch, two 32-point halves (wave-internal sync) ----
  f16x8 B0[2][4];
#pragma unroll
  for (int h = 0; h < 2; ++h) {
    if ((lane >> 5) == h) {
#pragma unroll
      for (int s = 0; s < 8; ++s)
        *(u32x4*)(scr + (lane & 31) * 128 + ((s ^ (lane & 7)) * 16)) = ((const u32x4*)fw)[s];
    }
    asm volatile("s_waitcnt lgkmcnt(0)" ::: "memory");
#pragma unroll
    for (int kt = 0; kt < 2; ++kt)
#pragma unroll
      for (int nn = 0; nn < 2; ++nn) {
        const int row = nn * 16 + r16;
        B0[kt][h * 2 + nn] = *(const f16x8*)(scr + row * 128 + (((4 * kt + g) ^ (row & 7)) * 16));
      }
    asm volatile("s_waitcnt lgkmcnt(0)" ::: "memory");
  }

  // ---- 3 hidden layers fully in registers, weights streamed from L2 w/ prefetch ----
  f16x8 Bx[4][4], By[4][4];
  layer_swapped<2>(ws + W0P_OFF, b0, B0, Bx, lane);
  layer_swapped<4>(ws + W1P_OFF, b1, Bx, By, lane);
  layer_swapped<4>(ws + W2P_OFF, b2, By, Bx, lane);

  // ---- output layer (M=16 padded, only row 0 real): preload all 4 frags, bias as C ----
  f16x8 Ab[4];
#pragma unroll
  for (int kt = 0; kt < 4; ++kt)
    Ab[kt] = *(const f16x8*)(ws + WOP_OFF + (kt * 64 + lane) * 16);
  const f32x4 bovec = (f32x4){bo, bo, bo, bo};
  f32x4 accO[4];
  __builtin_amdgcn_s_setprio(1);
#pragma unroll
  for (int nt = 0; nt < 4; ++nt)
    accO[nt] = __builtin_amdgcn_mfma_f32_16x16x32_f16(Ab[0], Bx[0][nt], bovec, 0, 0, 0);
#pragma unroll
  for (int kt = 1; kt < 4; ++kt) {
#pragma unroll
    for (int nt = 0; nt < 4; ++nt)
      accO[nt] = __builtin_amdgcn_mfma_f32_16x16x32_f16(Ab[kt], Bx[kt][nt], accO[nt], 0, 0, 0);
  }
  __builtin_amdgcn_s_setprio(0);

  // ---- coalesced store: broadcast row-0 values, one 256B wave store ----
  const float a0 = __shfl(accO[0][0], r16, 64);
  const float a1 = __shfl(accO[1][0], r16, 64);
  const float a2 = __shfl(accO[2][0], r16, 64);
  const float a3 = __shfl(accO[3][0], r16, 64);
  const float v = g == 0 ? a0 : g == 1 ? a1 : g == 2 ? a2 : a3;
  out[pbase + lane] = v;
}

extern "C" void kernel_launch(void* const* d_in, const int* in_sizes, int n_in,
                              void* d_out, int out_size, void* d_ws, size_t ws_size,
                              hipStream_t stream) {
  const float* time = (const float*)d_in[0];
  const float* xyz  = (const float*)d_in[1];
  const float* te0  = (const float*)d_in[2];
  const float* te1  = (const float*)d_in[3];
  const float* W0   = (const float*)d_in[4];
  const float* b0   = (const float*)d_in[5];
  const float* W1   = (const float*)d_in[6];
  const float* b1   = (const float*)d_in[7];
  const float* W2   = (const float*)d_in[8];
  const float* b2   = (const float*)d_in[9];
  const float* Wout = (const float*)d_in[10];
  const float* bout = (const float*)d_in[11];
  float* out = (float*)d_out;
  unsigned char* ws = (unsigned char*)d_ws;
  if (ws_size < WS_NEEDED) return;

  pack_weights<<<88, 64, 0, stream>>>(time, te0, te1, W0, W1, W2, Wout, ws);
  mlp_main<<<NPTS / 64, 64, LDS_TOTAL, stream>>>(xyz, b0, b1, b2, bout, ws, out);
}